// Round 2
// baseline (43977.612 us; speedup 1.0000x reference)
//
#include <hip/hip_runtime.h>
#include <stdint.h>

#define B_    512
#define SEQ_  256
#define H_    512
#define NSEQH (SEQ_ * H_)

using f32x4 = __attribute__((ext_vector_type(4))) float;
using s16x8 = __attribute__((ext_vector_type(8))) short;

__device__ inline unsigned short f2bf(float f) {
  union { float f; uint32_t u; } x; x.f = f;
  uint32_t u = x.u;
  uint32_t r = u + 0x7fffu + ((u >> 16) & 1u);
  return (unsigned short)(r >> 16);
}
__device__ inline float bf2f(unsigned short h) {
  union { float f; uint32_t u; } x; x.u = ((uint32_t)h) << 16;
  return x.f;
}
__device__ inline float h2f(unsigned short u) {
  _Float16 h;
  __builtin_memcpy(&h, &u, 2);
  return (float)h;
}
__device__ inline unsigned short f2h(float f) {
  _Float16 h = (_Float16)f;
  unsigned short u;
  __builtin_memcpy(&u, &h, 2);
  return u;
}
__device__ inline float sigf(float x) { return 1.0f / (1.0f + expf(-x)); }

// ---------------------------------------------------------------------------
// Split W (N x Ksrc fp32) into Ws (N x 2*Kpad bf16): [W_hi | W_lo].
// Optional zero column insertion at pad_at (layer-0 W: 63 x-features ->
// col 63 zero pad, h shifts to 64..575) so K-tiles of 64 stay homogeneous.
// ---------------------------------------------------------------------------
__global__ void split_weight(const float* __restrict__ W, short* __restrict__ Ws,
                             int N, int Ksrc, int Kpad, int pad_at) {
  int idx = blockIdx.x * blockDim.x + threadIdx.x;
  int total = N * Kpad;
  if (idx >= total) return;
  int n = idx / Kpad, c = idx - n * Kpad;
  int sc = c;
  if (pad_at >= 0) {
    if (c == pad_at) sc = -1;
    else if (c > pad_at) sc = c - 1;
  }
  float v = 0.f;
  if (sc >= 0 && sc < Ksrc) v = W[(size_t)n * Ksrc + sc];
  unsigned short hi = f2bf(v);
  unsigned short lo = f2bf(v - bf2f(hi));
  size_t base = (size_t)n * (2 * Kpad);
  Ws[base + c]        = (short)hi;
  Ws[base + Kpad + c] = (short)lo;
}

// Tm1T[t][b] = 1/log(dt + 2.7183) - 1   (transposed for coalesced epilogue)
__global__ void tm1_kernel(const float* __restrict__ in, float* __restrict__ Tm1T) {
  int idx = blockIdx.x * blockDim.x + threadIdx.x;
  if (idx >= B_ * SEQ_) return;
  int b = idx / SEQ_, t = idx - b * SEQ_;
  float dt = in[(size_t)b * (SEQ_ * 64) + t * 64 + 63];
  Tm1T[t * B_ + b] = 1.0f / logf(dt + 2.7183f) - 1.0f;
}

// diagnostic sentinel fill
__global__ void fill_kernel(float* __restrict__ out, int n, float v) {
  int i = blockIdx.x * blockDim.x + threadIdx.x;
  if (i < n) out[i] = v;
}

// ---------------------------------------------------------------------------
// Step GEMM with bf16x3 split precision: logical K' = 3K as blocks
// [A_hi*W_hi | A_lo*W_hi | A_hi*W_lo]; weight source stored as [hi|lo]
// (stride Kps = 2K), remapped per block. A built on the fly from fp32
// (or fp16 when XHALF, x-part only) sources.
//   GATES=false (GEMM1): h_upd = h + Tm1 * tanh(acc + bd), NF*16 cols/block.
//   GATES=true  (GEMM2): 16 j-cols across all 4 gates; LSTM cell update
//     epilogue; optional fp16 store of h into layer-output buffer.
// LDS tiles XOR-swizzled (byte ^= (row&7)<<4) for ds_read_b128.
// ---------------------------------------------------------------------------
template<int NF, bool GATES, bool XHALF>
__global__ __launch_bounds__(256) void gemm_step(
    const void* __restrict__ xsrc, int xstride, int c_inp_pad, int zero_col,
    const float* __restrict__ hsrc,
    const short* __restrict__ Wsp, int Kps, int K, int nK,
    const float* __restrict__ bias,
    const float* __restrict__ hin, const float* __restrict__ tm1,
    float* __restrict__ hupd_out,
    float* __restrict__ cbuf, float* __restrict__ hbuf,
    unsigned short* __restrict__ lo0buf, int s_store)
{
  constexpr int BROWS = NF * 16;
  __shared__ __align__(16) char As[64 * 128];
  __shared__ __align__(16) char Bs[BROWS * 128];
  const int tid = threadIdx.x;
  const int m0 = blockIdx.x * 64;
  const int n0 = blockIdx.y * (GATES ? 16 : 32);
  const int w = tid >> 6;
  const int l = tid & 63;

  f32x4 acc[NF];
#pragma unroll
  for (int i = 0; i < NF; ++i) acc[i] = (f32x4){0.f, 0.f, 0.f, 0.f};

  const int arow = tid >> 2;   // 0..63 (A tile row)
  const int aseg = tid & 3;    // 16-float segment within row

  int blk = 0, kk = 0;         // K'-block index and offset within logical K
  for (int kt = 0; kt < nK; ++kt) {
    const bool losel = (blk == 1);   // A-lo on block 1
    const int kbsrc = kk + (blk == 2 ? K : 0);  // W-lo region on block 2

    // ---- A stage: load fp32/fp16, convert hi/lo bf16, swizzled ds_write ----
    {
      const bool isx = (kk < c_inp_pad);
      float vraw[16];
      if (XHALF && isx) {
        const unsigned short* p = (const unsigned short*)xsrc
            + (size_t)(m0 + arow) * xstride + kk + aseg * 16;
        s16x8 h0 = *(const s16x8*)p;
        s16x8 h1 = *(const s16x8*)(p + 8);
#pragma unroll
        for (int j = 0; j < 8; ++j) {
          vraw[j]     = h2f((unsigned short)h0[j]);
          vraw[8 + j] = h2f((unsigned short)h1[j]);
        }
      } else {
        const float* bp = isx ? ((const float*)xsrc + kk) : (hsrc + (kk - c_inp_pad));
        const int str = isx ? xstride : H_;
        const float* p = bp + (size_t)(m0 + arow) * str + aseg * 16;
#pragma unroll
        for (int i = 0; i < 4; ++i) {
          f32x4 t = *(const f32x4*)(p + 4 * i);
          vraw[4 * i + 0] = t[0]; vraw[4 * i + 1] = t[1];
          vraw[4 * i + 2] = t[2]; vraw[4 * i + 3] = t[3];
        }
      }
      if (zero_col >= 0 && (kk < c_inp_pad)) {
        const int base_c = kk + aseg * 16;
#pragma unroll
        for (int j = 0; j < 16; ++j)
          if (base_c + j == zero_col) vraw[j] = 0.f;
      }
      const int rbyte = arow * 128 + aseg * 32;
      const int swz = (arow & 7) << 4;
#pragma unroll
      for (int hf = 0; hf < 2; ++hf) {
        s16x8 pk;
#pragma unroll
        for (int j = 0; j < 8; ++j) {
          float f = vraw[hf * 8 + j];
          unsigned short hh = f2bf(f);
          if (losel) hh = f2bf(f - bf2f(hh));
          pk[j] = (short)hh;
        }
        *(s16x8*)(As + ((rbyte + hf * 16) ^ swz)) = pk;
      }
    }

    // ---- B stage: bf16 weights, linear source, swizzled LDS dest ----
    {
#pragma unroll
      for (int c = tid; c < BROWS * 8; c += 256) {
        const int r = c >> 3, c16 = c & 7;
        const int src_n = GATES ? ((r >> 4) * H_ + n0 + (r & 15)) : (n0 + r);
        s16x8 d = *(const s16x8*)(Wsp + (size_t)src_n * Kps + kbsrc + c16 * 8);
        *(s16x8*)(Bs + ((r * 128 + c16 * 16) ^ ((r & 7) << 4))) = d;
      }
    }
    __syncthreads();

    // ---- compute: 2 sub-K of 32, NF MFMAs each ----
    {
      const int ar = w * 16 + (l & 15);
      const int koff = (l >> 4) * 16;
#pragma unroll
      for (int k2 = 0; k2 < 2; ++k2) {
        s16x8 af = *(const s16x8*)(As + ((ar * 128 + k2 * 64 + koff) ^ ((ar & 7) << 4)));
#pragma unroll
        for (int nf = 0; nf < NF; ++nf) {
          const int br = nf * 16 + (l & 15);
          s16x8 bf = *(const s16x8*)(Bs + ((br * 128 + k2 * 64 + koff) ^ ((br & 7) << 4)));
          acc[nf] = __builtin_amdgcn_mfma_f32_16x16x32_bf16(af, bf, acc[nf], 0, 0, 0);
        }
      }
    }
    __syncthreads();

    kk += 64;
    if (kk >= K) { kk = 0; ++blk; }
  }

  // ---- epilogue ----
  const int mrow0 = m0 + w * 16 + (l >> 4) * 4;
  if (!GATES) {
#pragma unroll
    for (int nf = 0; nf < NF; ++nf) {
      const int n_abs = n0 + nf * 16 + (l & 15);
      const float bv = bias[n_abs];
#pragma unroll
      for (int r = 0; r < 4; ++r) {
        const int m_abs = mrow0 + r;
        float cst = tanhf(acc[nf][r] + bv);
        hupd_out[(size_t)m_abs * H_ + n_abs] =
            hin[(size_t)m_abs * H_ + n_abs] + tm1[m_abs] * cst;
      }
    }
  } else {
    const int j_abs = n0 + (l & 15);
    const float bi = bias[j_abs];
    const float bfv = bias[H_ + j_abs];
    const float bo = bias[2 * H_ + j_abs];
    const float bg = bias[3 * H_ + j_abs];
#pragma unroll
    for (int r = 0; r < 4; ++r) {
      const int m_abs = mrow0 + r;
      float zi = acc[0][r] + bi;
      float zf = acc[1][r] + bfv;
      float zo = acc[2][r] + bo;
      float zg = acc[3][r] + bg;
      float co = cbuf[(size_t)m_abs * H_ + j_abs];
      float cn = sigf(zf) * co + sigf(zi) * tanhf(zg);
      float hn = sigf(zo) * tanhf(cn);
      cbuf[(size_t)m_abs * H_ + j_abs] = cn;
      hbuf[(size_t)m_abs * H_ + j_abs] = hn;
      if (lo0buf)
        lo0buf[(size_t)m_abs * NSEQH + (size_t)s_store * H_ + j_abs] = f2h(hn);
    }
  }
}

extern "C" void kernel_launch(void* const* d_in, const int* in_sizes, int n_in,
                              void* d_out, int out_size, void* d_ws, size_t ws_size,
                              hipStream_t stream) {
  const float* inputs = (const float*)d_in[0];
  const float* W0  = (const float*)d_in[1];
  const float* b0  = (const float*)d_in[2];
  const float* Wd0 = (const float*)d_in[3];
  const float* bd0 = (const float*)d_in[4];
  const float* W1  = (const float*)d_in[5];
  const float* b1  = (const float*)d_in[6];
  const float* Wd1 = (const float*)d_in[7];
  const float* bd1 = (const float*)d_in[8];

  char* ws = (char*)d_ws;
  size_t off = 0;
  auto alloc = [&](size_t bytes) -> char* {
    char* p = ws + off;
    off += (bytes + 1023) & ~(size_t)1023;
    return p;
  };
  unsigned short* lo0 = (unsigned short*)alloc((size_t)B_ * SEQ_ * H_ * 2);  // fp16, 128 MiB
  float* hbuf = (float*)alloc((size_t)B_ * H_ * 4);
  float* cbuf = (float*)alloc((size_t)B_ * H_ * 4);
  float* hupd = (float*)alloc((size_t)B_ * H_ * 4);
  float* Tm1T = (float*)alloc((size_t)SEQ_ * B_ * 4);
  short* Wd0s = (short*)alloc((size_t)512 * 1024 * 2);
  short* W0s  = (short*)alloc((size_t)2048 * 1152 * 2);
  short* Wd1s = (short*)alloc((size_t)512 * 1024 * 2);
  short* W1s  = (short*)alloc((size_t)2048 * 2048 * 2);

  if (off > ws_size) {
    // workspace too small: deterministic sentinel encoding ws MiB into d_out
    fill_kernel<<<(out_size + 255) / 256, 256, 0, stream>>>(
        (float*)d_out, out_size, (float)(ws_size >> 20));
    return;
  }

  // --- prep: split weights [hi|lo], Tm1 table ---
  {
    int thr = 256, tot;
    tot = 512 * 512;
    split_weight<<<(tot + thr - 1) / thr, thr, 0, stream>>>(Wd0, Wd0s, 512, 512, 512, -1);
    split_weight<<<(tot + thr - 1) / thr, thr, 0, stream>>>(Wd1, Wd1s, 512, 512, 512, -1);
    tot = 2048 * 576;
    split_weight<<<(tot + thr - 1) / thr, thr, 0, stream>>>(W0, W0s, 2048, 575, 576, 63);
    tot = 2048 * 1024;
    split_weight<<<(tot + thr - 1) / thr, thr, 0, stream>>>(W1, W1s, 2048, 1024, 1024, -1);
    tot = B_ * SEQ_;
    tm1_kernel<<<(tot + thr - 1) / thr, thr, 0, stream>>>(inputs, Tm1T);
  }

  for (int layer = 0; layer < 2; ++layer) {
    hipMemsetAsync(hbuf, 0, (size_t)B_ * H_ * 4, stream);
    hipMemsetAsync(cbuf, 0, (size_t)B_ * H_ * 4, stream);
    const short* Wds = layer ? Wd1s : Wd0s;
    const short* Wsg = layer ? W1s : W0s;
    const float* bd  = layer ? bd1 : bd0;
    const float* bb  = layer ? b1 : b0;
    const int Kps2 = layer ? 2048 : 1152;
    const int K2   = layer ? 1024 : 576;
    const int nK2  = layer ? 48 : 27;
    const int cip  = layer ? 512 : 64;
    const int zc   = layer ? -1 : 63;
    const int xstr = layer ? NSEQH : (SEQ_ * 64);

    for (int s = 0; s < SEQ_; ++s) {
      const int torig = SEQ_ - 1 - s;
      // GEMM1: h_upd = h + Tm1 * tanh(h @ Wd.T + bd)
      gemm_step<2, false, false><<<dim3(8, 16), 256, 0, stream>>>(
          nullptr, 0, 0, -1, hbuf, Wds, 1024, 512, 24, bd,
          hbuf, Tm1T + (size_t)torig * B_, hupd,
          nullptr, nullptr, nullptr, 0);
      // GEMM2: z = [x, h_upd] @ W.T + b -> cell update
      if (layer == 0) {
        const void* xs = (const void*)(inputs + (size_t)torig * 64);
        gemm_step<4, true, false><<<dim3(8, 32), 256, 0, stream>>>(
            xs, xstr, cip, zc, hupd, Wsg, Kps2, K2, nK2, bb,
            nullptr, nullptr, nullptr,
            cbuf, hbuf, lo0, s);
      } else {
        const void* xs = (const void*)(lo0 + (size_t)torig * H_);
        gemm_step<4, true, true><<<dim3(8, 32), 256, 0, stream>>>(
            xs, xstr, cip, zc, hupd, Wsg, Kps2, K2, nK2, bb,
            nullptr, nullptr, nullptr,
            cbuf, hbuf, nullptr, 0);
      }
    }
  }

  hipMemcpyAsync(d_out, hbuf, (size_t)B_ * H_ * 4, hipMemcpyDeviceToDevice, stream);
}

// Round 3
// 33155.917 us; speedup vs baseline: 1.3264x; 1.3264x over previous
//
#include <hip/hip_runtime.h>
#include <stdint.h>

#define B_    512
#define SEQ_  256
#define H_    512
#define NSEQH (SEQ_ * H_)

using f32x4 = __attribute__((ext_vector_type(4))) float;
using s16x8 = __attribute__((ext_vector_type(8))) short;

__device__ inline unsigned short f2bf(float f) {
  union { float f; uint32_t u; } x; x.f = f;
  uint32_t u = x.u;
  uint32_t r = u + 0x7fffu + ((u >> 16) & 1u);
  return (unsigned short)(r >> 16);
}
__device__ inline float bf2f(unsigned short h) {
  union { float f; uint32_t u; } x; x.u = ((uint32_t)h) << 16;
  return x.f;
}
__device__ inline float h2f(unsigned short u) {
  _Float16 h;
  __builtin_memcpy(&h, &u, 2);
  return (float)h;
}
__device__ inline unsigned short f2h(float f) {
  _Float16 h = (_Float16)f;
  unsigned short u;
  __builtin_memcpy(&u, &h, 2);
  return u;
}
__device__ inline float sigf(float x) { return 1.0f / (1.0f + expf(-x)); }

// async global->LDS, 16B per lane; LDS dest = wave-uniform base + lane*16
__device__ inline void gload16(const void* g, void* l) {
  __builtin_amdgcn_global_load_lds(
      (const __attribute__((address_space(1))) void*)g,
      (__attribute__((address_space(3))) void*)l, 16, 0, 0);
}

// ---------------------------------------------------------------------------
// Split W (N x Ksrc fp32) into Ws (N x 2*Kpad bf16): [W_hi | W_lo].
// Optional zero-column insertion at pad_at (layer-0 W: col 63 zero pad).
// ---------------------------------------------------------------------------
__global__ void split_weight(const float* __restrict__ W, short* __restrict__ Ws,
                             int N, int Ksrc, int Kpad, int pad_at) {
  int idx = blockIdx.x * blockDim.x + threadIdx.x;
  int total = N * Kpad;
  if (idx >= total) return;
  int n = idx / Kpad, c = idx - n * Kpad;
  int sc = c;
  if (pad_at >= 0) {
    if (c == pad_at) sc = -1;
    else if (c > pad_at) sc = c - 1;
  }
  float v = 0.f;
  if (sc >= 0 && sc < Ksrc) v = W[(size_t)n * Ksrc + sc];
  unsigned short hi = f2bf(v);
  unsigned short lo = f2bf(v - bf2f(hi));
  size_t base = (size_t)n * (2 * Kpad);
  Ws[base + c]        = (short)hi;
  Ws[base + Kpad + c] = (short)lo;
}

// inputs fp32 -> bf16 hi/lo (same [B][SEQ][64] layout; col63=dt harmless,
// the weight's zero pad column kills its contribution)
__global__ void split_x(const float* __restrict__ in, short* __restrict__ xhi,
                        short* __restrict__ xlo, int n) {
  int i = blockIdx.x * blockDim.x + threadIdx.x;
  if (i >= n) return;
  float v = in[i];
  unsigned short hi = f2bf(v);
  xhi[i] = (short)hi;
  xlo[i] = (short)f2bf(v - bf2f(hi));
}

// Tm1T[t][b] = 1/log(dt + 2.7183) - 1
__global__ void tm1_kernel(const float* __restrict__ in, float* __restrict__ Tm1T) {
  int idx = blockIdx.x * blockDim.x + threadIdx.x;
  if (idx >= B_ * SEQ_) return;
  int b = idx / SEQ_, t = idx - b * SEQ_;
  float dt = in[(size_t)b * (SEQ_ * 64) + t * 64 + 63];
  Tm1T[t * B_ + b] = 1.0f / logf(dt + 2.7183f) - 1.0f;
}

__global__ void fill_kernel(float* __restrict__ out, int n, float v) {
  int i = blockIdx.x * blockDim.x + threadIdx.x;
  if (i < n) out[i] = v;
}

// ---------------------------------------------------------------------------
// GEMM1: h_upd = h + Tm1*tanh(h @ Wd.T + bd). 32x32 tile, grid(n=16, m=16),
// 256 thr (4 waves: wm=w&1 rows, wn=w>>1 cols). K' = 3*512, 24 tiles.
// All sources pre-split bf16 -> global_load_lds staging, swizzled-source.
// CVT: also convert lo0[:,torig,:] fp16 -> xh hi/lo slab for layer-1 GEMM2.
// ---------------------------------------------------------------------------
template<bool CVT>
__global__ __launch_bounds__(256) void g1_kernel(
    const short* __restrict__ hhi, const short* __restrict__ hlo,
    const short* __restrict__ Wds, const float* __restrict__ bd,
    const float* __restrict__ hbuf, const float* __restrict__ tm1,
    short* __restrict__ huhi, short* __restrict__ hulo,
    const unsigned short* __restrict__ lo0_t,
    short* __restrict__ xhhi, short* __restrict__ xhlo)
{
  __shared__ __align__(16) char As[2][4096];
  __shared__ __align__(16) char Bs[2][4096];
  const int tid = threadIdx.x;
  const int n0 = blockIdx.x * 32;
  const int m0 = blockIdx.y * 32;
  const int w = tid >> 6, l = tid & 63;

  const int sr = tid >> 3;          // staged row 0..31
  const int scs = (tid & 7) ^ (sr & 7);  // pre-swizzled source chunk

  f32x4 acc = {0.f, 0.f, 0.f, 0.f};

  auto stage = [&](int buf, int kt) {
    const int blk = kt >> 3;
    const int kk = (kt & 7) << 6;
    const short* Asrc = (blk == 1) ? hlo : hhi;
    const int boff = kk + ((blk == 2) ? 512 : 0);
    gload16(Asrc + (size_t)(m0 + sr) * H_ + kk + scs * 8,
            (char*)As[buf] + w * 1024);
    gload16(Wds + (size_t)(n0 + sr) * 1024 + boff + scs * 8,
            (char*)Bs[buf] + w * 1024);
  };

  stage(0, 0);
  asm volatile("s_waitcnt vmcnt(0)" ::: "memory");
  __syncthreads();

  const int wm = w & 1, wn = w >> 1;
  const int ar = wm * 16 + (l & 15);
  const int br = wn * 16 + (l & 15);
  const int koff = (l >> 4) * 16;
  const int aswz = (ar & 7) << 4;
  const int bswz = (br & 7) << 4;

  for (int kt = 0; kt < 24; ++kt) {
    const int buf = kt & 1;
    if (kt + 1 < 24) stage(buf ^ 1, kt + 1);
#pragma unroll
    for (int k2 = 0; k2 < 2; ++k2) {
      s16x8 af = *(const s16x8*)(As[buf] + ((ar * 128 + k2 * 64 + koff) ^ aswz));
      s16x8 bf = *(const s16x8*)(Bs[buf] + ((br * 128 + k2 * 64 + koff) ^ bswz));
      acc = __builtin_amdgcn_mfma_f32_16x16x32_bf16(af, bf, acc, 0, 0, 0);
    }
    asm volatile("s_waitcnt vmcnt(0)" ::: "memory");
    __syncthreads();
  }

  const int n_abs = n0 + wn * 16 + (l & 15);
  const int mbase = m0 + wm * 16 + (l >> 4) * 4;
  const float bv = bd[n_abs];
#pragma unroll
  for (int r = 0; r < 4; ++r) {
    const int m_abs = mbase + r;
    float cst = tanhf(acc[r] + bv);
    float hu = hbuf[(size_t)m_abs * H_ + n_abs] + tm1[m_abs] * cst;
    unsigned short hi = f2bf(hu);
    huhi[(size_t)m_abs * H_ + n_abs] = (short)hi;
    hulo[(size_t)m_abs * H_ + n_abs] = (short)f2bf(hu - bf2f(hi));
    if (CVT) {
      float xv = h2f(lo0_t[(size_t)m_abs * NSEQH + n_abs]);
      unsigned short xh = f2bf(xv);
      xhhi[(size_t)m_abs * H_ + n_abs] = (short)xh;
      xhlo[(size_t)m_abs * H_ + n_abs] = (short)f2bf(xv - bf2f(xh));
    }
  }
}

// ---------------------------------------------------------------------------
// GEMM2: z = [x,h_upd] @ W.T + b -> LSTM cell update. 64 m-rows, 16 j-cols
// x 4 gates (64 B-rows) per block, grid(n=32, m=8), 256 thr, acc[4].
// K' = 3K, NT tiles; all sources pre-split bf16 via global_load_lds.
// ---------------------------------------------------------------------------
template<int K, int TPB, int KPS, int XK, int XSTRIDE, bool STORE_LO0>
__global__ __launch_bounds__(256) void g2_kernel(
    const short* __restrict__ xhi, const short* __restrict__ xlo,
    const short* __restrict__ huhi, const short* __restrict__ hulo,
    const short* __restrict__ Wsp, const float* __restrict__ bias,
    float* __restrict__ cbuf, float* __restrict__ hbuf,
    short* __restrict__ hhi, short* __restrict__ hlo,
    unsigned short* __restrict__ lo0_t)
{
  constexpr int NT = 3 * K / 64;
  __shared__ __align__(16) char As[2][8192];
  __shared__ __align__(16) char Bs[2][8192];
  const int tid = threadIdx.x;
  const int n0 = blockIdx.x * 16;
  const int m0 = blockIdx.y * 64;
  const int w = tid >> 6, l = tid & 63;

  f32x4 acc[4];
#pragma unroll
  for (int i = 0; i < 4; ++i) acc[i] = (f32x4){0.f, 0.f, 0.f, 0.f};

  auto stage = [&](int buf, int kt) {
    const int blk = kt / TPB;
    const int kk = (kt - blk * TPB) << 6;
    const bool lo_a = (blk == 1);
    const int boff = kk + ((blk == 2) ? K : 0);
#pragma unroll
    for (int j = 0; j < 2; ++j) {
      const int s = tid + j * 256;
      const int r = s >> 3;
      const int cs = (s & 7) ^ (r & 7);
      const short* asrc;
      size_t aoff;
      if (kk < XK) {
        asrc = lo_a ? xlo : xhi;
        aoff = (size_t)(m0 + r) * XSTRIDE + kk + cs * 8;
      } else {
        asrc = lo_a ? hulo : huhi;
        aoff = (size_t)(m0 + r) * H_ + (kk - XK) + cs * 8;
      }
      gload16(asrc + aoff, (char*)As[buf] + j * 4096 + w * 1024);
      const int src_n = (r >> 4) * H_ + n0 + (r & 15);
      gload16(Wsp + (size_t)src_n * KPS + boff + cs * 8,
              (char*)Bs[buf] + j * 4096 + w * 1024);
    }
  };

  stage(0, 0);
  asm volatile("s_waitcnt vmcnt(0)" ::: "memory");
  __syncthreads();

  const int ar = w * 16 + (l & 15);
  const int koff = (l >> 4) * 16;
  const int aswz = (ar & 7) << 4;

  for (int kt = 0; kt < NT; ++kt) {
    const int buf = kt & 1;
    if (kt + 1 < NT) stage(buf ^ 1, kt + 1);
#pragma unroll
    for (int k2 = 0; k2 < 2; ++k2) {
      s16x8 af = *(const s16x8*)(As[buf] + ((ar * 128 + k2 * 64 + koff) ^ aswz));
#pragma unroll
      for (int nf = 0; nf < 4; ++nf) {
        const int br = nf * 16 + (l & 15);
        s16x8 bf = *(const s16x8*)(Bs[buf] + ((br * 128 + k2 * 64 + koff) ^ ((br & 7) << 4)));
        acc[nf] = __builtin_amdgcn_mfma_f32_16x16x32_bf16(af, bf, acc[nf], 0, 0, 0);
      }
    }
    asm volatile("s_waitcnt vmcnt(0)" ::: "memory");
    __syncthreads();
  }

  const int j_abs = n0 + (l & 15);
  const float bi  = bias[j_abs];
  const float bfv = bias[H_ + j_abs];
  const float bo  = bias[2 * H_ + j_abs];
  const float bg  = bias[3 * H_ + j_abs];
#pragma unroll
  for (int r = 0; r < 4; ++r) {
    const int m_abs = m0 + w * 16 + (l >> 4) * 4 + r;
    float zi = acc[0][r] + bi;
    float zf = acc[1][r] + bfv;
    float zo = acc[2][r] + bo;
    float zg = acc[3][r] + bg;
    float co = cbuf[(size_t)m_abs * H_ + j_abs];
    float cn = sigf(zf) * co + sigf(zi) * tanhf(zg);
    float hn = sigf(zo) * tanhf(cn);
    cbuf[(size_t)m_abs * H_ + j_abs] = cn;
    hbuf[(size_t)m_abs * H_ + j_abs] = hn;
    unsigned short hi = f2bf(hn);
    hhi[(size_t)m_abs * H_ + j_abs] = (short)hi;
    hlo[(size_t)m_abs * H_ + j_abs] = (short)f2bf(hn - bf2f(hi));
    if (STORE_LO0)
      lo0_t[(size_t)m_abs * NSEQH + j_abs] = f2h(hn);
  }
}

extern "C" void kernel_launch(void* const* d_in, const int* in_sizes, int n_in,
                              void* d_out, int out_size, void* d_ws, size_t ws_size,
                              hipStream_t stream) {
  const float* inputs = (const float*)d_in[0];
  const float* W0  = (const float*)d_in[1];
  const float* b0  = (const float*)d_in[2];
  const float* Wd0 = (const float*)d_in[3];
  const float* bd0 = (const float*)d_in[4];
  const float* W1  = (const float*)d_in[5];
  const float* b1  = (const float*)d_in[6];
  const float* Wd1 = (const float*)d_in[7];
  const float* bd1 = (const float*)d_in[8];

  char* ws = (char*)d_ws;
  size_t off = 0;
  auto alloc = [&](size_t bytes) -> char* {
    char* p = ws + off;
    off += (bytes + 1023) & ~(size_t)1023;
    return p;
  };
  unsigned short* lo0 = (unsigned short*)alloc((size_t)B_ * SEQ_ * H_ * 2); // fp16
  short* xinhi = (short*)alloc((size_t)B_ * SEQ_ * 64 * 2);
  short* xinlo = (short*)alloc((size_t)B_ * SEQ_ * 64 * 2);
  float* hbuf  = (float*)alloc((size_t)B_ * H_ * 4);
  float* cbuf  = (float*)alloc((size_t)B_ * H_ * 4);
  short* hhi   = (short*)alloc((size_t)B_ * H_ * 2);
  short* hlo   = (short*)alloc((size_t)B_ * H_ * 2);
  short* huhi  = (short*)alloc((size_t)B_ * H_ * 2);
  short* hulo  = (short*)alloc((size_t)B_ * H_ * 2);
  short* xhhi  = (short*)alloc((size_t)B_ * H_ * 2);
  short* xhlo  = (short*)alloc((size_t)B_ * H_ * 2);
  float* Tm1T  = (float*)alloc((size_t)SEQ_ * B_ * 4);
  short* Wd0s  = (short*)alloc((size_t)512 * 1024 * 2);
  short* Wd1s  = (short*)alloc((size_t)512 * 1024 * 2);
  short* W0s   = (short*)alloc((size_t)2048 * 1152 * 2);
  short* W1s   = (short*)alloc((size_t)2048 * 2048 * 2);

  if (off > ws_size) {
    fill_kernel<<<(out_size + 255) / 256, 256, 0, stream>>>(
        (float*)d_out, out_size, (float)(ws_size >> 20));
    return;
  }

  {
    int thr = 256, tot;
    tot = 512 * 512;
    split_weight<<<(tot + thr - 1) / thr, thr, 0, stream>>>(Wd0, Wd0s, 512, 512, 512, -1);
    split_weight<<<(tot + thr - 1) / thr, thr, 0, stream>>>(Wd1, Wd1s, 512, 512, 512, -1);
    tot = 2048 * 576;
    split_weight<<<(tot + thr - 1) / thr, thr, 0, stream>>>(W0, W0s, 2048, 575, 576, 63);
    tot = 2048 * 1024;
    split_weight<<<(tot + thr - 1) / thr, thr, 0, stream>>>(W1, W1s, 2048, 1024, 1024, -1);
    tot = B_ * SEQ_ * 64;
    split_x<<<(tot + thr - 1) / thr, thr, 0, stream>>>(inputs, xinhi, xinlo, tot);
    tot = B_ * SEQ_;
    tm1_kernel<<<(tot + thr - 1) / thr, thr, 0, stream>>>(inputs, Tm1T);
  }

  for (int layer = 0; layer < 2; ++layer) {
    hipMemsetAsync(hbuf, 0, (size_t)B_ * H_ * 4, stream);
    hipMemsetAsync(cbuf, 0, (size_t)B_ * H_ * 4, stream);
    hipMemsetAsync(hhi, 0, (size_t)B_ * H_ * 2, stream);
    hipMemsetAsync(hlo, 0, (size_t)B_ * H_ * 2, stream);

    for (int s = 0; s < SEQ_; ++s) {
      const int torig = SEQ_ - 1 - s;
      if (layer == 0) {
        g1_kernel<false><<<dim3(16, 16), 256, 0, stream>>>(
            hhi, hlo, Wd0s, bd0, hbuf, Tm1T + (size_t)torig * B_,
            huhi, hulo, nullptr, nullptr, nullptr);
        g2_kernel<576, 9, 1152, 64, SEQ_ * 64, true><<<dim3(32, 8), 256, 0, stream>>>(
            xinhi + (size_t)torig * 64, xinlo + (size_t)torig * 64,
            huhi, hulo, W0s, b0, cbuf, hbuf, hhi, hlo,
            lo0 + (size_t)s * H_);
      } else {
        g1_kernel<true><<<dim3(16, 16), 256, 0, stream>>>(
            hhi, hlo, Wd1s, bd1, hbuf, Tm1T + (size_t)torig * B_,
            huhi, hulo, lo0 + (size_t)torig * H_, xhhi, xhlo);
        g2_kernel<1024, 16, 2048, 512, H_, false><<<dim3(32, 8), 256, 0, stream>>>(
            xhhi, xhlo, huhi, hulo, W1s, b1, cbuf, hbuf, hhi, hlo, nullptr);
      }
    }
  }

  hipMemcpyAsync(d_out, hbuf, (size_t)B_ * H_ * 4, hipMemcpyDeviceToDevice, stream);
}